// Round 1
// baseline (384.106 us; speedup 1.0000x reference)
//
#include <hip/hip_runtime.h>

// SSIM loss, fused: (32,3,512,512) fp32, 11x11 avg pools, out = 1 - mean(ssim_map).
//
// R4 structure: one block = 64x22 output tile (was 64x32).
//  Four box-filtered planes needed: H = (Sum p, Sum t, Sum p^2+t^2, Sum p*t) -> float4.
//
//  LDS = 32 rows x 64 float4 = 32768 B exactly -> 5 blocks/CU (was 3 at 44 KB).
//  No pad column: bank conflicts broken by XOR swizzle col ^ (row&7), which is
//  conflict-free for stage-B b128 writes (8 bank-groups x 8 lanes) and keeps
//  stage-C reads contiguous-permuted (conflict-free).
//
//  Stage B (horizontal 11-sums): ALL 256 threads: (halo row j in 0..31, 8-col
//    run xr in 0..7). 6 aligned float4 loads per tensor covering [x0-8, x0+16),
//    loads are UNCONDITIONAL with clamped addresses + cndmask-zero for OOB so
//    all 12 loads pipeline under one vmcnt wait. Slide 11-window in registers,
//    write 8 float4 H cells.
//  Stage C (vertical 11-sums): lane = x (contiguous b128 reads), wave w owns
//    6 output rows (last wave 4); 10-row running sum in registers.
//  Block reduce -> one double atomic per block; scratch reuses sH after barrier.

#define IMGW 512
#define IMGPIX (IMGW * IMGW)
#define TW 64
#define TH 22
#define NROWS 32          // TH + 10 halo
#define NIMG 96

__global__ __launch_bounds__(256, 5)
void ssim_partial(const float* __restrict__ pred,
                  const float* __restrict__ target,
                  double* __restrict__ accum)
{
    __shared__ float4 sH[NROWS * 64];   // 32768 B exactly

    const int tid = threadIdx.x;
    const int bx = blockIdx.x, by = blockIdx.y, img = blockIdx.z;
    const float* __restrict__ p = pred   + (size_t)img * IMGPIX;
    const float* __restrict__ t = target + (size_t)img * IMGPIX;
    const int gy0 = by * TH;

    // ---- Stage B: horizontal 11-sums of 4 planes, sliding in registers ----
    {
        const int j  = tid >> 3;          // halo row 0..31
        const int xr = tid & 7;           // 8-col run
        const int rv = gy0 - 5 + j;       // image row (may be OOB)
        const bool rowok = (unsigned)rv < (unsigned)IMGW;
        const int rvc = rv < 0 ? 0 : (rv > IMGW - 1 ? IMGW - 1 : rv);
        const int xbase = bx * TW + xr * 8;

        float fp[24], ft[24];
#pragma unroll
        for (int c = 0; c < 6; ++c) {
            const int gx = xbase - 8 + 4 * c;     // multiple of 4 -> aligned float4
            const bool ok = rowok && ((unsigned)gx < (unsigned)IMGW);
            const int gxc = gx < 0 ? 0 : (gx > IMGW - 4 ? IMGW - 4 : gx);
            const size_t off = (size_t)rvc * IMGW + gxc;
            const float4 pv = *(const float4*)(p + off);
            const float4 tv = *(const float4*)(t + off);
            const float m = ok ? 1.f : 0.f;
            fp[4*c+0] = pv.x * m; fp[4*c+1] = pv.y * m;
            fp[4*c+2] = pv.z * m; fp[4*c+3] = pv.w * m;
            ft[4*c+0] = tv.x * m; ft[4*c+1] = tv.y * m;
            ft[4*c+2] = tv.z * m; ft[4*c+3] = tv.w * m;
        }
        // output x = xbase+k has window indices i = k+3 .. k+13 (i: x = xbase-8+i)
        float s1 = 0.f, s2 = 0.f, s3 = 0.f, s4 = 0.f;
#pragma unroll
        for (int i = 3; i <= 13; ++i) {
            s1 += fp[i];
            s2 += ft[i];
            s3 += fp[i] * fp[i] + ft[i] * ft[i];
            s4 += fp[i] * ft[i];
        }
        const int rbase = j << 6;
        const int sw = j & 7;
#pragma unroll
        for (int k = 0; k < 8; ++k) {
            if (k > 0) {
                const int a = k + 13, b = k + 2;
                s1 += fp[a] - fp[b];
                s2 += ft[a] - ft[b];
                s3 += (fp[a] * fp[a] + ft[a] * ft[a])
                    - (fp[b] * fp[b] + ft[b] * ft[b]);
                s4 += fp[a] * ft[a] - fp[b] * ft[b];
            }
            sH[rbase | ((xr * 8 + k) ^ sw)] = make_float4(s1, s2, s3, s4);
        }
    }
    __syncthreads();

    // ---- Stage C: vertical 11-sums (lane = x), SSIM formula ----
    const float inv = 1.0f / 121.0f;
    const float C1 = 1e-4f, C2 = 9e-4f;
    const int lane = tid & 63;
    const int w    = tid >> 6;
    const int ry0  = w * 6;               // waves own rows {0..5,6..11,12..17,18..21}

    float4 r[6];
    float4 S = {0.f, 0.f, 0.f, 0.f};
#pragma unroll
    for (int i = 0; i < 6; ++i) {
        const int row = ry0 + i;
        r[i] = sH[(row << 6) | (lane ^ (row & 7))];
        S.x += r[i].x; S.y += r[i].y; S.z += r[i].z; S.w += r[i].w;
    }
#pragma unroll
    for (int i = 6; i < 10; ++i) {
        const int row = ry0 + i;
        const float4 a = sH[(row << 6) | (lane ^ (row & 7))];
        S.x += a.x; S.y += a.y; S.z += a.z; S.w += a.w;
    }
    float local = 0.f;
#pragma unroll
    for (int k = 0; k < 6; ++k) {
        const int ry = ry0 + k;
        if (ry >= TH || gy0 + ry >= IMGW) break;   // suffix-only exits
        const int row = ry + 10;
        const float4 nw = sH[(row << 6) | (lane ^ (row & 7))];
        const float W1 = S.x + nw.x;      // 11-row window sums
        const float W2 = S.y + nw.y;
        const float W3 = S.z + nw.z;
        const float W4 = S.w + nw.w;
        // advance running 10-row sum
        S.x = W1 - r[k].x; S.y = W2 - r[k].y;
        S.z = W3 - r[k].z; S.w = W4 - r[k].w;

        const float mu1 = W1 * inv, mu2 = W2 * inv;
        const float E3  = W3 * inv, E12 = W4 * inv;
        const float mu11 = mu1 * mu1, mu22 = mu2 * mu2, mu12 = mu1 * mu2;
        const float num = (2.f * mu12 + C1) * (2.f * (E12 - mu12) + C2);
        const float den = (mu11 + mu22 + C1) * ((E3 - mu11 - mu22) + C2);
        local += num / den;
    }

    // ---- block reduce -> one double atomic per block (scratch reuses sH) ----
#pragma unroll
    for (int off = 32; off > 0; off >>= 1)
        local += __shfl_down(local, off, 64);
    __syncthreads();                       // all sH reads complete
    if (lane == 0) ((float*)sH)[w] = local;
    __syncthreads();
    if (tid == 0) {
        const float* red = (const float*)sH;
        atomicAdd(accum, (double)(red[0] + red[1] + red[2] + red[3]));
    }
}

__global__ void ssim_finalize(const double* __restrict__ accum,
                              float* __restrict__ out) {
    const double n = 25165824.0;  // 32*3*512*512
    out[0] = (float)(1.0 - accum[0] / n);
}

extern "C" void kernel_launch(void* const* d_in, const int* in_sizes, int n_in,
                              void* d_out, int out_size, void* d_ws, size_t ws_size,
                              hipStream_t stream) {
    const float* pred   = (const float*)d_in[0];
    const float* target = (const float*)d_in[1];
    float* out = (float*)d_out;
    double* accum = (double*)d_ws;

    hipMemsetAsync(d_ws, 0, sizeof(double), stream);

    dim3 grid(IMGW / TW, (IMGW + TH - 1) / TH, NIMG);  // 8 x 24 x 96
    dim3 block(256);
    ssim_partial<<<grid, block, 0, stream>>>(pred, target, accum);
    ssim_finalize<<<1, 1, 0, stream>>>(accum, out);
}